// Round 5
// baseline (634.798 us; speedup 1.0000x reference)
//
#include <hip/hip_runtime.h>

#define NEGV (-10000.0f)

constexpr int B_ = 512;
constexpr int S_ = 1024;
constexpr int NL_ = 49;
constexpr int L_ = 51;   // NL + 2; start = 49, end = 50

__device__ __forceinline__ float readlane_f(float v, int l) {
    return __int_as_float(__builtin_amdgcn_readlane(__float_as_int(v), l));
}

// v = max(v, dpp_move(v, CTRL)); CTRL must be a compile-time constant.
template <int CTRL>
__device__ __forceinline__ float dpp_max_step(float v) {
    int sh = __builtin_amdgcn_update_dpp(__float_as_int(v), __float_as_int(v),
                                         CTRL, 0xf, 0xf, false);
    return fmaxf(v, __int_as_float(sh));
}

// Full 64-lane max -> wave-uniform scalar (SGPR). Pure VALU (DPP), no LDS pipe.
__device__ __forceinline__ float wave_max_sgpr(float v) {
    v = dpp_max_step<0x111>(v);  // row_shr:1
    v = dpp_max_step<0x112>(v);  // row_shr:2
    v = dpp_max_step<0x114>(v);  // row_shr:4
    v = dpp_max_step<0x118>(v);  // row_shr:8
    v = dpp_max_step<0x142>(v);  // row_bcast:15
    v = dpp_max_step<0x143>(v);  // row_bcast:31
    return readlane_f(v, 63);
}

__global__ __launch_bounds__(64, 1) void crf_fwd(
    const float* __restrict__ logits,      // (B, S, NL)
    const float* __restrict__ transition,  // (L, L)
    const int*   __restrict__ labels,      // (B, S)
    const int*   __restrict__ lens,        // (B,)
    float*       __restrict__ out)         // (B,)
{
    const int b    = blockIdx.x;
    const int lane = threadIdx.x;
    const int len  = __builtin_amdgcn_readfirstlane(lens[b]);  // wave-uniform, >= 1

    const float* __restrict__ lg  = logits + (size_t)b * (S_ * NL_);
    const int*   __restrict__ lab = labels + (size_t)b * S_;

    // ---- per-lane transition row (rows 0..48; start row dead after t=0,
    //      end column identically 0 in exp-space), exponentiated ----
    float Erow[NL_];
    float Tend, estart;
    {
        const bool st = (lane < NL_);
        const float* trow = transition + ((lane < L_) ? lane : 0) * L_;
        #pragma unroll
        for (int j = 0; j < NL_; ++j) {
            float tv = trow[j];
            Erow[j] = st ? __expf(tv) : 0.0f;
        }
        estart = __expf(trow[NL_]);                    // exp(T[lane][start])
        Tend   = (lane < L_) ? transition[(L_ - 1) * L_ + lane] : NEGV;
    }

    // ---- gold score: lane-parallel over time ----
    float g = 0.0f;
    for (int t = lane; t < S_; t += 64) {
        if (t < len) {
            int c = lab[t];
            int p = (t == 0) ? (L_ - 2) : lab[t - 1];
            g += lg[t * NL_ + c] + transition[c * L_ + p];
            if (t == len - 1) g += transition[(L_ - 1) * L_ + c];  // end transition
        }
    }
    #pragma unroll
    for (int o = 32; o >= 1; o >>= 1) g += __shfl_xor(g, o, 64);

    // Opaque zero base VGPR: lets the backend fold (zero + 4j) into the DS
    // offset: field of each ds_bpermute (no per-j v_mov address materialization).
    int zero_addr;
    asm("v_mov_b32 %0, 0" : "=v"(zero_addr));

    // ---- forward scan ----
    // t = 0 analytically: alpha_i = lg[0][i] + log(exp(T[i][start]))
    float alpha;
    {
        float lg0 = (lane < NL_) ? lg[lane] : NEGV;
        alpha = (lane < NL_) ? (lg0 + __logf(estart)) : NEGV;
    }
    float M = 0.0f;   // max of alpha BEFORE step 0 (start vector) = 0; stale-by-1

    auto loadlg = [&](int t) -> float {
        float v = NEGV;
        if (lane < NL_) v = lg[t * NL_ + lane];
        return v;
    };

    float b0 = loadlg(1), b1 = loadlg(2), b2 = loadlg(3), b3 = loadlg(4);
    float b4 = loadlg(5), b5 = loadlg(6), b6 = loadlg(7), b7 = loadlg(8);

    auto substep = [&](float cur, int t) {
        float p  = __expf(alpha - M);       // bounded: alpha - stale_max small
        int   pi = __float_as_int(p);
        // Broadcast p_j to all lanes: 49 INDEPENDENT ds_bpermute (VGPR dest,
        // LDS-pipe pipelined, no SGPR writeback serialization, no ds_write
        // round-trip). Bits identical to the readlane version.
        float ps[NL_];
        #pragma unroll
        for (int j = 0; j < NL_; ++j)
            ps[j] = __int_as_float(
                __builtin_amdgcn_ds_bpermute(zero_addr + 4 * j, pi));
        float Mn = wave_max_sgpr(alpha);    // DPP chain overlaps bpermute latency
        // y_i = sum_{j<49} E[i][j] * p_j  — same accumulators/order as before:
        float y0 = 0.f, y1 = 0.f, y2 = 0.f, y3 = 0.f;
        #pragma unroll
        for (int j = 0; j < 48; j += 4) {
            y0 = fmaf(ps[j + 0], Erow[j + 0], y0);
            y1 = fmaf(ps[j + 1], Erow[j + 1], y1);
            y2 = fmaf(ps[j + 2], Erow[j + 2], y2);
            y3 = fmaf(ps[j + 3], Erow[j + 3], y3);
        }
        y0 = fmaf(ps[48], Erow[48], y0);
        float y = (y0 + y1) + (y2 + y3);
        float anew = cur + M + __logf(y);
        if (t < len && lane < NL_) alpha = anew;   // uniform t<len; cndmask on lane
        M = Mn;
    };

    const int tEnd = 1 + (((len - 1) + 7) & ~7);   // steps t = 1 .. len-1, padded to 8
    for (int t = 1; t < tEnd; t += 8) {
        int t8  = t + 8;  t8  = (t8  < S_) ? t8  : (S_ - 1);
        int t9  = t + 9;  t9  = (t9  < S_) ? t9  : (S_ - 1);
        int t10 = t + 10; t10 = (t10 < S_) ? t10 : (S_ - 1);
        int t11 = t + 11; t11 = (t11 < S_) ? t11 : (S_ - 1);
        int t12 = t + 12; t12 = (t12 < S_) ? t12 : (S_ - 1);
        int t13 = t + 13; t13 = (t13 < S_) ? t13 : (S_ - 1);
        int t14 = t + 14; t14 = (t14 < S_) ? t14 : (S_ - 1);
        int t15 = t + 15; t15 = (t15 < S_) ? t15 : (S_ - 1);
        substep(b0, t + 0); b0 = loadlg(t8);
        substep(b1, t + 1); b1 = loadlg(t9);
        substep(b2, t + 2); b2 = loadlg(t10);
        substep(b3, t + 3); b3 = loadlg(t11);
        substep(b4, t + 4); b4 = loadlg(t12);
        substep(b5, t + 5); b5 = loadlg(t13);
        substep(b6, t + 6); b6 = loadlg(t14);
        substep(b7, t + 7); b7 = loadlg(t15);
    }

    // ---- norm = LSE_i(alpha_i + T[end, i]) ----
    float x = (lane < L_) ? (alpha + Tend) : NEGV;
    float mx = x;
    #pragma unroll
    for (int o = 32; o >= 1; o >>= 1) mx = fmaxf(mx, __shfl_xor(mx, o, 64));
    float e = __expf(x - mx);
    #pragma unroll
    for (int o = 32; o >= 1; o >>= 1) e += __shfl_xor(e, o, 64);
    float norm = mx + __logf(e);

    if (lane == 0) out[b] = g - norm;
}

extern "C" void kernel_launch(void* const* d_in, const int* in_sizes, int n_in,
                              void* d_out, int out_size, void* d_ws, size_t ws_size,
                              hipStream_t stream) {
    const float* logits     = (const float*)d_in[0];
    const float* transition = (const float*)d_in[1];
    const int*   labels     = (const int*)d_in[2];
    const int*   lens       = (const int*)d_in[3];
    float*       out        = (float*)d_out;
    crf_fwd<<<dim3(B_), dim3(64), 0, stream>>>(logits, transition, labels, lens, out);
}

// Round 6
// 629.695 us; speedup vs baseline: 1.0081x; 1.0081x over previous
//
#include <hip/hip_runtime.h>

#define NEGV (-10000.0f)

constexpr int B_ = 512;
constexpr int S_ = 1024;
constexpr int NL_ = 49;
constexpr int L_ = 51;   // NL + 2; start = 49, end = 50

__device__ __forceinline__ float readlane_f(float v, int l) {
    return __int_as_float(__builtin_amdgcn_readlane(__float_as_int(v), l));
}

// v = max(v, dpp_move(v, CTRL)); CTRL must be a compile-time constant.
template <int CTRL>
__device__ __forceinline__ float dpp_max_step(float v) {
    int sh = __builtin_amdgcn_update_dpp(__float_as_int(v), __float_as_int(v),
                                         CTRL, 0xf, 0xf, false);
    return fmaxf(v, __int_as_float(sh));
}

// Full 64-lane max -> wave-uniform scalar (SGPR). Pure VALU (DPP), no LDS pipe.
__device__ __forceinline__ float wave_max_sgpr(float v) {
    v = dpp_max_step<0x111>(v);  // row_shr:1
    v = dpp_max_step<0x112>(v);  // row_shr:2
    v = dpp_max_step<0x114>(v);  // row_shr:4
    v = dpp_max_step<0x118>(v);  // row_shr:8
    v = dpp_max_step<0x142>(v);  // row_bcast:15
    v = dpp_max_step<0x143>(v);  // row_bcast:31
    return readlane_f(v, 63);
}

__global__ __launch_bounds__(64, 1) void crf_fwd(
    const float* __restrict__ logits,      // (B, S, NL)
    const float* __restrict__ transition,  // (L, L)
    const int*   __restrict__ labels,      // (B, S)
    const int*   __restrict__ lens,        // (B,)
    float*       __restrict__ out)         // (B,)
{
    const int b    = blockIdx.x;
    const int lane = threadIdx.x;
    const int len  = __builtin_amdgcn_readfirstlane(lens[b]);  // wave-uniform, >= 1

    const float* __restrict__ lg  = logits + (size_t)b * (S_ * NL_);
    const int*   __restrict__ lab = labels + (size_t)b * S_;

    // p broadcast buffer: 52 floats = 13 float4. Single wave -> no barrier needed;
    // compiler orders same-address DS ops via lgkmcnt.
    __shared__ __align__(16) float pbuf[52];
    if (lane >= NL_ && lane < 52) pbuf[lane] = 0.0f;   // make pad reads defined

    // ---- per-lane transition row (rows 0..48; start row dead after t=0,
    //      end column identically 0 in exp-space), exponentiated ----
    float Erow[NL_];
    float Tend, estart;
    {
        const bool st = (lane < NL_);
        const float* trow = transition + ((lane < L_) ? lane : 0) * L_;
        #pragma unroll
        for (int j = 0; j < NL_; ++j) {
            float tv = trow[j];
            Erow[j] = st ? __expf(tv) : 0.0f;
        }
        estart = __expf(trow[NL_]);                    // exp(T[lane][start])
        Tend   = (lane < L_) ? transition[(L_ - 1) * L_ + lane] : NEGV;
    }

    // ---- gold score: lane-parallel over time ----
    float g = 0.0f;
    for (int t = lane; t < S_; t += 64) {
        if (t < len) {
            int c = lab[t];
            int p = (t == 0) ? (L_ - 2) : lab[t - 1];
            g += lg[t * NL_ + c] + transition[c * L_ + p];
            if (t == len - 1) g += transition[(L_ - 1) * L_ + c];  // end transition
        }
    }
    #pragma unroll
    for (int o = 32; o >= 1; o >>= 1) g += __shfl_xor(g, o, 64);

    // ---- forward scan ----
    // t = 0 analytically: alpha_i = lg[0][i] + log(exp(T[i][start]))
    float alpha;
    {
        float lg0 = (lane < NL_) ? lg[lane] : NEGV;
        alpha = (lane < NL_) ? (lg0 + __logf(estart)) : NEGV;
    }
    float M = 0.0f;   // max of alpha BEFORE step 0 (start vector) = 0; stale-by-1

    auto loadlg = [&](int t) -> float {
        float v = NEGV;
        if (lane < NL_) v = lg[t * NL_ + lane];
        return v;
    };

    float b0 = loadlg(1), b1 = loadlg(2), b2 = loadlg(3), b3 = loadlg(4);
    float b4 = loadlg(5), b5 = loadlg(6), b6 = loadlg(7), b7 = loadlg(8);

    auto substep = [&](float cur, int t) {
        float p = __expf(alpha - M);          // bounded: alpha - stale_max small
        if (lane < NL_) pbuf[lane] = p;       // ds_write_b32, earliest possible
        float Mn = wave_max_sgpr(alpha);      // DPP chain covers write latency
        // Broadcast-read p (wave-uniform addr -> LDS broadcast, conflict-free).
        // Consume each quad IMMEDIATELY: <=2 quads live, no q[13] staging array
        // (R3's 52-VGPR staging block caused the spill regression).
        const float4* pv = (const float4*)pbuf;
        float y0 = 0.f, y1 = 0.f, y2 = 0.f, y3 = 0.f;
        #pragma unroll
        for (int k = 0; k < 12; ++k) {
            float4 q = pv[k];
            y0 = fmaf(q.x, Erow[4 * k + 0], y0);
            y1 = fmaf(q.y, Erow[4 * k + 1], y1);
            y2 = fmaf(q.z, Erow[4 * k + 2], y2);
            y3 = fmaf(q.w, Erow[4 * k + 3], y3);
        }
        y0 = fmaf(pbuf[48], Erow[48], y0);    // ds_read_b32, uniform
        float y = (y0 + y1) + (y2 + y3);
        float anew = cur + M + __logf(y);
        if (t < len && lane < NL_) alpha = anew;   // uniform t<len; cndmask on lane
        M = Mn;
    };

    const int tEnd = 1 + (((len - 1) + 7) & ~7);   // steps t = 1 .. len-1, padded to 8
    for (int t = 1; t < tEnd; t += 8) {
        int t8  = t + 8;  t8  = (t8  < S_) ? t8  : (S_ - 1);
        int t9  = t + 9;  t9  = (t9  < S_) ? t9  : (S_ - 1);
        int t10 = t + 10; t10 = (t10 < S_) ? t10 : (S_ - 1);
        int t11 = t + 11; t11 = (t11 < S_) ? t11 : (S_ - 1);
        int t12 = t + 12; t12 = (t12 < S_) ? t12 : (S_ - 1);
        int t13 = t + 13; t13 = (t13 < S_) ? t13 : (S_ - 1);
        int t14 = t + 14; t14 = (t14 < S_) ? t14 : (S_ - 1);
        int t15 = t + 15; t15 = (t15 < S_) ? t15 : (S_ - 1);
        substep(b0, t + 0); b0 = loadlg(t8);
        substep(b1, t + 1); b1 = loadlg(t9);
        substep(b2, t + 2); b2 = loadlg(t10);
        substep(b3, t + 3); b3 = loadlg(t11);
        substep(b4, t + 4); b4 = loadlg(t12);
        substep(b5, t + 5); b5 = loadlg(t13);
        substep(b6, t + 6); b6 = loadlg(t14);
        substep(b7, t + 7); b7 = loadlg(t15);
    }

    // ---- norm = LSE_i(alpha_i + T[end, i]) ----
    float x = (lane < L_) ? (alpha + Tend) : NEGV;
    float mx = x;
    #pragma unroll
    for (int o = 32; o >= 1; o >>= 1) mx = fmaxf(mx, __shfl_xor(mx, o, 64));
    float e = __expf(x - mx);
    #pragma unroll
    for (int o = 32; o >= 1; o >>= 1) e += __shfl_xor(e, o, 64);
    float norm = mx + __logf(e);

    if (lane == 0) out[b] = g - norm;
}

extern "C" void kernel_launch(void* const* d_in, const int* in_sizes, int n_in,
                              void* d_out, int out_size, void* d_ws, size_t ws_size,
                              hipStream_t stream) {
    const float* logits     = (const float*)d_in[0];
    const float* transition = (const float*)d_in[1];
    const int*   labels     = (const int*)d_in[2];
    const int*   lens       = (const int*)d_in[3];
    float*       out        = (float*)d_out;
    crf_fwd<<<dim3(B_), dim3(64), 0, stream>>>(logits, transition, labels, lens, out);
}

// Round 9
// 486.933 us; speedup vs baseline: 1.3037x; 1.2932x over previous
//
#include <hip/hip_runtime.h>

#define NEGV (-10000.0f)

constexpr int B_ = 512;
constexpr int S_ = 1024;
constexpr int NL_ = 49;
constexpr int L_ = 51;   // NL + 2; start = 49, end = 50

typedef __attribute__((ext_vector_type(4))) float f32x4;

__device__ __forceinline__ float readlane_f(float v, int l) {
    return __int_as_float(__builtin_amdgcn_readlane(__float_as_int(v), l));
}

// v = max(v, dpp_move(v, CTRL)); CTRL must be a compile-time constant.
template <int CTRL>
__device__ __forceinline__ float dpp_max_step(float v) {
    int sh = __builtin_amdgcn_update_dpp(__float_as_int(v), __float_as_int(v),
                                         CTRL, 0xf, 0xf, false);
    return fmaxf(v, __int_as_float(sh));
}

// Full 64-lane max -> wave-uniform scalar (SGPR). Pure VALU (DPP), no LDS pipe.
__device__ __forceinline__ float wave_max_sgpr(float v) {
    v = dpp_max_step<0x111>(v);  // row_shr:1
    v = dpp_max_step<0x112>(v);  // row_shr:2
    v = dpp_max_step<0x114>(v);  // row_shr:4
    v = dpp_max_step<0x118>(v);  // row_shr:8
    v = dpp_max_step<0x142>(v);  // row_bcast:15
    v = dpp_max_step<0x143>(v);  // row_bcast:31
    return readlane_f(v, 63);
}

__global__ __launch_bounds__(64, 1) void crf_fwd(
    const float* __restrict__ logits,      // (B, S, NL)
    const float* __restrict__ transition,  // (L, L)
    const int*   __restrict__ labels,      // (B, S)
    const int*   __restrict__ lens,        // (B,)
    float*       __restrict__ out)         // (B,)
{
    const int b    = blockIdx.x;
    const int lane = threadIdx.x;
    const int len  = __builtin_amdgcn_readfirstlane(lens[b]);  // wave-uniform, >= 1

    const float* __restrict__ lg  = logits + (size_t)b * (S_ * NL_);
    const int*   __restrict__ lab = labels + (size_t)b * S_;

    // p broadcast buffer: all 64 lanes write each step (lanes >= NL_ write 0.0,
    // since their alpha stays NEGV -> exp flushes to 0). Only [0..48] is read.
    __shared__ __align__(16) float pbuf[64];

    // ---- per-lane transition row (rows 0..48; start row dead after t=0,
    //      end column identically 0 in exp-space), exponentiated ----
    float Erow[NL_];
    float Tend, estart;
    {
        const bool st = (lane < NL_);
        const float* trow = transition + ((lane < L_) ? lane : 0) * L_;
        #pragma unroll
        for (int j = 0; j < NL_; ++j) {
            float tv = trow[j];
            Erow[j] = st ? __expf(tv) : 0.0f;
        }
        estart = __expf(trow[NL_]);                    // exp(T[lane][start])
        Tend   = (lane < L_) ? transition[(L_ - 1) * L_ + lane] : NEGV;
    }

    // ---- gold score: lane-parallel over time ----
    float g = 0.0f;
    for (int t = lane; t < S_; t += 64) {
        if (t < len) {
            int c = lab[t];
            int p = (t == 0) ? (L_ - 2) : lab[t - 1];
            g += lg[t * NL_ + c] + transition[c * L_ + p];
            if (t == len - 1) g += transition[(L_ - 1) * L_ + c];  // end transition
        }
    }
    #pragma unroll
    for (int o = 32; o >= 1; o >>= 1) g += __shfl_xor(g, o, 64);

    // ---- forward scan ----
    // t = 0 analytically: alpha_i = lg[0][i] + log(exp(T[i][start]))
    float alpha;
    {
        float lg0 = (lane < NL_) ? lg[lane] : NEGV;
        alpha = (lane < NL_) ? (lg0 + __logf(estart)) : NEGV;
    }
    float M = 0.0f;   // max of alpha BEFORE step 0 (start vector) = 0; stale-by-1

    auto loadlg = [&](int t) -> float {
        float v = NEGV;
        if (lane < NL_) v = lg[t * NL_ + lane];
        return v;
    };

    float b0 = loadlg(1), b1 = loadlg(2), b2 = loadlg(3), b3 = loadlg(4);
    float b4 = loadlg(5), b5 = loadlg(6), b6 = loadlg(7), b7 = loadlg(8);

    auto substep = [&](float cur, int t) {
        float p = __expf(alpha - M);     // lanes >= NL_: exp(NEGV - M) == 0
        pbuf[lane] = p;                  // unconditional ds_write_b32
        float Mn = wave_max_sgpr(alpha); // DPP chain overlaps write drain
        // Issue ALL broadcast reads (wave-uniform addr -> LDS broadcast,
        // conflict-free) and FENCE them with a data-dependence tie: the empty
        // asm takes every staged value as "+v", so no ds_read can be sunk past
        // it -> 13 back-to-back reads, ONE lgkmcnt wait, then 49 fmas.
        const f32x4* pv = (const f32x4*)pbuf;
        f32x4 q0  = pv[0],  q1  = pv[1],  q2  = pv[2],  q3  = pv[3];
        f32x4 q4  = pv[4],  q5  = pv[5],  q6  = pv[6],  q7  = pv[7];
        f32x4 q8  = pv[8],  q9  = pv[9],  q10 = pv[10], q11 = pv[11];
        float p48 = pbuf[48];
        asm volatile(""
            : "+v"(q0), "+v"(q1), "+v"(q2),  "+v"(q3),
              "+v"(q4), "+v"(q5), "+v"(q6),  "+v"(q7),
              "+v"(q8), "+v"(q9), "+v"(q10), "+v"(q11), "+v"(p48));
        // y_i = sum_{j<49} E[i][j] * p_j  — same accumulators/order as R2:
        float y0 = 0.f, y1 = 0.f, y2 = 0.f, y3 = 0.f;
        #define FMA4(Q, base)                      \
            y0 = fmaf(Q.x, Erow[(base) + 0], y0);  \
            y1 = fmaf(Q.y, Erow[(base) + 1], y1);  \
            y2 = fmaf(Q.z, Erow[(base) + 2], y2);  \
            y3 = fmaf(Q.w, Erow[(base) + 3], y3);
        FMA4(q0,  0)  FMA4(q1,  4)  FMA4(q2,  8)  FMA4(q3, 12)
        FMA4(q4, 16)  FMA4(q5, 20)  FMA4(q6, 24)  FMA4(q7, 28)
        FMA4(q8, 32)  FMA4(q9, 36)  FMA4(q10, 40) FMA4(q11, 44)
        #undef FMA4
        y0 = fmaf(p48, Erow[48], y0);
        float y = (y0 + y1) + (y2 + y3);
        float anew = cur + M + __logf(y);
        if (t < len && lane < NL_) alpha = anew;   // uniform t<len; cndmask on lane
        M = Mn;
    };

    const int tEnd = 1 + (((len - 1) + 7) & ~7);   // steps t = 1 .. len-1, padded to 8
    for (int t = 1; t < tEnd; t += 8) {
        int t8  = t + 8;  t8  = (t8  < S_) ? t8  : (S_ - 1);
        int t9  = t + 9;  t9  = (t9  < S_) ? t9  : (S_ - 1);
        int t10 = t + 10; t10 = (t10 < S_) ? t10 : (S_ - 1);
        int t11 = t + 11; t11 = (t11 < S_) ? t11 : (S_ - 1);
        int t12 = t + 12; t12 = (t12 < S_) ? t12 : (S_ - 1);
        int t13 = t + 13; t13 = (t13 < S_) ? t13 : (S_ - 1);
        int t14 = t + 14; t14 = (t14 < S_) ? t14 : (S_ - 1);
        int t15 = t + 15; t15 = (t15 < S_) ? t15 : (S_ - 1);
        substep(b0, t + 0); b0 = loadlg(t8);
        substep(b1, t + 1); b1 = loadlg(t9);
        substep(b2, t + 2); b2 = loadlg(t10);
        substep(b3, t + 3); b3 = loadlg(t11);
        substep(b4, t + 4); b4 = loadlg(t12);
        substep(b5, t + 5); b5 = loadlg(t13);
        substep(b6, t + 6); b6 = loadlg(t14);
        substep(b7, t + 7); b7 = loadlg(t15);
    }

    // ---- norm = LSE_i(alpha_i + T[end, i]) ----
    float x = (lane < L_) ? (alpha + Tend) : NEGV;
    float mx = x;
    #pragma unroll
    for (int o = 32; o >= 1; o >>= 1) mx = fmaxf(mx, __shfl_xor(mx, o, 64));
    float e = __expf(x - mx);
    #pragma unroll
    for (int o = 32; o >= 1; o >>= 1) e += __shfl_xor(e, o, 64);
    float norm = mx + __logf(e);

    if (lane == 0) out[b] = g - norm;
}

extern "C" void kernel_launch(void* const* d_in, const int* in_sizes, int n_in,
                              void* d_out, int out_size, void* d_ws, size_t ws_size,
                              hipStream_t stream) {
    const float* logits     = (const float*)d_in[0];
    const float* transition = (const float*)d_in[1];
    const int*   labels     = (const int*)d_in[2];
    const int*   lens       = (const int*)d_in[3];
    float*       out        = (float*)d_out;
    crf_fwd<<<dim3(B_), dim3(64), 0, stream>>>(logits, transition, labels, lens, out);
}

// Round 10
// 462.008 us; speedup vs baseline: 1.3740x; 1.0540x over previous
//
#include <hip/hip_runtime.h>

#define NEGV (-10000.0f)

constexpr int B_ = 512;
constexpr int S_ = 1024;
constexpr int NL_ = 49;
constexpr int L_ = 51;   // NL + 2; start = 49, end = 50

typedef __attribute__((ext_vector_type(4))) float f32x4;

__device__ __forceinline__ float readlane_f(float v, int l) {
    return __int_as_float(__builtin_amdgcn_readlane(__float_as_int(v), l));
}

template <int CTRL>
__device__ __forceinline__ float dpp_max_step(float v) {
    int sh = __builtin_amdgcn_update_dpp(__float_as_int(v), __float_as_int(v),
                                         CTRL, 0xf, 0xf, false);
    return fmaxf(v, __int_as_float(sh));
}

// Full 64-lane max -> wave-uniform scalar (SGPR). Pure VALU (DPP), no LDS pipe.
__device__ __forceinline__ float wave_max_sgpr(float v) {
    v = dpp_max_step<0x111>(v);  // row_shr:1
    v = dpp_max_step<0x112>(v);  // row_shr:2
    v = dpp_max_step<0x114>(v);  // row_shr:4
    v = dpp_max_step<0x118>(v);  // row_shr:8
    v = dpp_max_step<0x142>(v);  // row_bcast:15
    v = dpp_max_step<0x143>(v);  // row_bcast:31
    return readlane_f(v, 63);
}

__global__ __launch_bounds__(64, 1) void crf_fwd(
    const float* __restrict__ logits,      // (B, S, NL)
    const float* __restrict__ transition,  // (L, L)
    const int*   __restrict__ labels,      // (B, S)
    const int*   __restrict__ lens,        // (B,)
    float*       __restrict__ out)         // (B,)
{
    const int b    = blockIdx.x;
    const int lane = threadIdx.x;
    const int len  = __builtin_amdgcn_readfirstlane(lens[b]);  // wave-uniform, >= 1

    const float* __restrict__ lg  = logits + (size_t)b * (S_ * NL_);
    const int*   __restrict__ lab = labels + (size_t)b * S_;

    // Broadcast buffer for exp-space state P. All 64 lanes write; [0..48] read.
    __shared__ __align__(16) float pbuf[64];

    // ---- per-lane transition row, exponentiated (rows 0..48) ----
    float Erow[NL_];
    float Tend, estart;
    {
        const bool st = (lane < NL_);
        const float* trow = transition + ((lane < L_) ? lane : 0) * L_;
        #pragma unroll
        for (int j = 0; j < NL_; ++j) {
            float tv = trow[j];
            Erow[j] = st ? __expf(tv) : 0.0f;
        }
        estart = __expf(trow[NL_]);                    // exp(T[lane][start])
        Tend   = (lane < L_) ? transition[(L_ - 1) * L_ + lane] : NEGV;
    }

    // ---- gold score: lane-parallel over time ----
    float g = 0.0f;
    for (int t = lane; t < S_; t += 64) {
        if (t < len) {
            int c = lab[t];
            int p = (t == 0) ? (L_ - 2) : lab[t - 1];
            g += lg[t * NL_ + c] + transition[c * L_ + p];
            if (t == len - 1) g += transition[(L_ - 1) * L_ + c];  // end transition
        }
    }
    #pragma unroll
    for (int o = 32; o >= 1; o >>= 1) g += __shfl_xor(g, o, 64);

    // ---- forward scan, EXP-SPACE linear recurrence ----
    // P_i = exp(alpha_i - S*ln2); P_{t} = 2^{-k_t} * D_t * E * P_{t-1}.
    // exp(logit) is off-chain (prefetched); log happens ONCE after the loop;
    // per-step rescale is an EXACT power-of-2 fold into d (zero chain cost).
    float P = 0.0f;
    if (lane < NL_) P = __expf(lg[lane]) * estart;      // t = 0
    pbuf[lane] = P;                                     // pre-fill broadcast buf

    int   S = 0;          // total base-2 shifts applied (wave-uniform)
    int   kc;             // shift for the upcoming step
    float scale_f;        // 2^{-kc}
    auto mk_scale = [&](float Mx) {
        int e = (__float_as_int(Mx) >> 23) & 255;
        if (e < 1) e = 1;                       // zero/denormal guard
        kc      = e - 127;
        scale_f = __int_as_float((254 - e) << 23);   // exact 2^{-kc}
    };
    mk_scale(wave_max_sgpr(P));

    auto loadlg = [&](int t) -> float {
        float v = NEGV;
        if (lane < NL_) v = lg[t * NL_ + lane];
        return v;
    };

    float b0 = loadlg(1), b1 = loadlg(2), b2 = loadlg(3), b3 = loadlg(4);
    float b4 = loadlg(5), b5 = loadlg(6), b6 = loadlg(7), b7 = loadlg(8);

    auto substep = [&](float cur, int t) {
        float Mx = wave_max_sgpr(P);         // off-chain: next step's scale
        float d  = __expf(cur) * scale_f;    // off-chain: cur ready 8 steps early
        // Grouped broadcast reads (wave-uniform addr -> conflict-free LDS
        // broadcast). asm fence ties all staged values: reads issue
        // back-to-back, one wait, then the fma block.
        const f32x4* pv = (const f32x4*)pbuf;
        f32x4 q0  = pv[0],  q1  = pv[1],  q2  = pv[2],  q3  = pv[3];
        f32x4 q4  = pv[4],  q5  = pv[5],  q6  = pv[6],  q7  = pv[7];
        f32x4 q8  = pv[8],  q9  = pv[9],  q10 = pv[10], q11 = pv[11];
        float p48 = pbuf[48];
        asm volatile(""
            : "+v"(q0), "+v"(q1), "+v"(q2),  "+v"(q3),
              "+v"(q4), "+v"(q5), "+v"(q6),  "+v"(q7),
              "+v"(q8), "+v"(q9), "+v"(q10), "+v"(q11), "+v"(p48));
        float y0 = 0.f, y1 = 0.f, y2 = 0.f, y3 = 0.f;
        #define FMA4(Q, base)                      \
            y0 = fmaf(Q.x, Erow[(base) + 0], y0);  \
            y1 = fmaf(Q.y, Erow[(base) + 1], y1);  \
            y2 = fmaf(Q.z, Erow[(base) + 2], y2);  \
            y3 = fmaf(Q.w, Erow[(base) + 3], y3);
        FMA4(q0,  0)  FMA4(q1,  4)  FMA4(q2,  8)  FMA4(q3, 12)
        FMA4(q4, 16)  FMA4(q5, 20)  FMA4(q6, 24)  FMA4(q7, 28)
        FMA4(q8, 32)  FMA4(q9, 36)  FMA4(q10, 40) FMA4(q11, 44)
        #undef FMA4
        float y  = (y0 + y1) + (y2 + y3);
        float Pn = d * y;                    // lanes >= NL_: y == 0 -> Pn == 0
        pbuf[lane] = Pn;                     // next step's broadcast; pad-step
                                             // writes only feed discarded math
        const bool live = (t < len);         // wave-uniform
        if (live && lane < NL_) P = Pn;      // freeze after len (epilogue uses P)
        if (live) S += kc;                   // uniform scalar bookkeeping
        mk_scale(Mx);                        // kc/scale for next step
    };

    const int tEnd = 1 + (((len - 1) + 7) & ~7);   // steps t = 1 .. len-1, padded to 8
    for (int t = 1; t < tEnd; t += 8) {
        int t8  = t + 8;  t8  = (t8  < S_) ? t8  : (S_ - 1);
        int t9  = t + 9;  t9  = (t9  < S_) ? t9  : (S_ - 1);
        int t10 = t + 10; t10 = (t10 < S_) ? t10 : (S_ - 1);
        int t11 = t + 11; t11 = (t11 < S_) ? t11 : (S_ - 1);
        int t12 = t + 12; t12 = (t12 < S_) ? t12 : (S_ - 1);
        int t13 = t + 13; t13 = (t13 < S_) ? t13 : (S_ - 1);
        int t14 = t + 14; t14 = (t14 < S_) ? t14 : (S_ - 1);
        int t15 = t + 15; t15 = (t15 < S_) ? t15 : (S_ - 1);
        substep(b0, t + 0); b0 = loadlg(t8);
        substep(b1, t + 1); b1 = loadlg(t9);
        substep(b2, t + 2); b2 = loadlg(t10);
        substep(b3, t + 3); b3 = loadlg(t11);
        substep(b4, t + 4); b4 = loadlg(t12);
        substep(b5, t + 5); b5 = loadlg(t13);
        substep(b6, t + 6); b6 = loadlg(t14);
        substep(b7, t + 7); b7 = loadlg(t15);
    }

    // ---- back to log-space ONCE: alpha_i = log(P_i) + S*ln2 ----
    float alpha = logf(P) + (float)S * 0.69314718056f;   // P==0 -> -inf (ok in LSE)

    // ---- norm = LSE_i(alpha_i + T[end, i]) ----
    float x = (lane < L_) ? (alpha + Tend) : NEGV;
    float mx = x;
    #pragma unroll
    for (int o = 32; o >= 1; o >>= 1) mx = fmaxf(mx, __shfl_xor(mx, o, 64));
    float e = __expf(x - mx);
    #pragma unroll
    for (int o = 32; o >= 1; o >>= 1) e += __shfl_xor(e, o, 64);
    float norm = mx + __logf(e);

    if (lane == 0) out[b] = g - norm;
}

extern "C" void kernel_launch(void* const* d_in, const int* in_sizes, int n_in,
                              void* d_out, int out_size, void* d_ws, size_t ws_size,
                              hipStream_t stream) {
    const float* logits     = (const float*)d_in[0];
    const float* transition = (const float*)d_in[1];
    const int*   labels     = (const int*)d_in[2];
    const int*   lens       = (const int*)d_in[3];
    float*       out        = (float*)d_out;
    crf_fwd<<<dim3(B_), dim3(64), 0, stream>>>(logits, transition, labels, lens, out);
}